// Round 3
// baseline (243.711 us; speedup 1.0000x reference)
//
#include <hip/hip_runtime.h>
#include <hip/hip_bf16.h>
#include <math.h>

#define V_N   6890
#define N_PTS 16384
#define D_IN  700
#define D_INP 704      // padded K for GEMM1
#define D_HID 256
#define D_OUT 283
#define NCHUNK 16
#define CHUNK  431     // ceil(6890/16)

// ws layout (float units; all 16B aligned)
#define RINV_OFF 0              // V*9 -> 62016
#define KP4_OFF  62016          // V*4 floats -> 27584 (16B aligned: 62016*4%16==0)
#define KNN_OFF  89600          // 16384 ints
#define PD_OFF   105984         // 16384*16 doubles = 524288 floats
#define PI_OFF   630272         // 16384*16 ints = 262144 floats
#define WT1_OFF  892416         // 256*704 bf16 = 90112 floats
#define WT2_OFF  982528         // 256*256 bf16 = 32768 floats
#define WT3_OFF  1015296        // 32768 floats
#define X_OFF    1048064        // 16384*704 bf16 = 5767168 floats
#define H1_OFF   6815232        // 16384*256 bf16 = 2097152 floats
#define H2_OFF   8912384        // 2097152 floats
// end ~11.0M floats = ~44 MB

typedef __attribute__((ext_vector_type(8))) short short8;
typedef __attribute__((ext_vector_type(4))) float f32x4;

__device__ __forceinline__ unsigned short f2bf(float f) {
    unsigned int u = __builtin_bit_cast(unsigned int, f);
    u += 0x7fffu + ((u >> 16) & 1u);   // RNE
    return (unsigned short)(u >> 16);
}

__device__ __forceinline__ void glds16(const void* g, void* l) {
    __builtin_amdgcn_global_load_lds(
        (const __attribute__((address_space(1))) void*)g,
        (__attribute__((address_space(3))) void*)l, 16, 0, 0);
}

// ---------------- prep: per-vertex inv(4x4)[:3,:3] + packed (x,y,z,|k|^2) ----------------
__global__ __launch_bounds__(256) void prep_kernel(
    const float* __restrict__ trans, const float* __restrict__ keyp,
    float* __restrict__ rinv, float4* __restrict__ kp4)
{
    int v = blockIdx.x * 256 + threadIdx.x;
    if (v >= V_N) return;
    float m[16];
#pragma unroll
    for (int i = 0; i < 16; ++i) m[i] = trans[i * V_N + v];

    float i0  =  m[5]*m[10]*m[15] - m[5]*m[11]*m[14] - m[9]*m[6]*m[15] + m[9]*m[7]*m[14] + m[13]*m[6]*m[11] - m[13]*m[7]*m[10];
    float i4  = -m[4]*m[10]*m[15] + m[4]*m[11]*m[14] + m[8]*m[6]*m[15] - m[8]*m[7]*m[14] - m[12]*m[6]*m[11] + m[12]*m[7]*m[10];
    float i8  =  m[4]*m[9]*m[15]  - m[4]*m[11]*m[13] - m[8]*m[5]*m[15] + m[8]*m[7]*m[13] + m[12]*m[5]*m[11] - m[12]*m[7]*m[9];
    float i12 = -m[4]*m[9]*m[14]  + m[4]*m[10]*m[13] + m[8]*m[5]*m[14] - m[8]*m[6]*m[13] - m[12]*m[5]*m[10] + m[12]*m[6]*m[9];
    float i1  = -m[1]*m[10]*m[15] + m[1]*m[11]*m[14] + m[9]*m[2]*m[15] - m[9]*m[3]*m[14] - m[13]*m[2]*m[11] + m[13]*m[3]*m[10];
    float i5  =  m[0]*m[10]*m[15] - m[0]*m[11]*m[14] - m[8]*m[2]*m[15] + m[8]*m[3]*m[14] + m[12]*m[2]*m[11] - m[12]*m[3]*m[10];
    float i9  = -m[0]*m[9]*m[15]  + m[0]*m[11]*m[13] + m[8]*m[1]*m[15] - m[8]*m[3]*m[13] - m[12]*m[1]*m[11] + m[12]*m[3]*m[9];
    float i2  =  m[1]*m[6]*m[15]  - m[1]*m[7]*m[14]  - m[5]*m[2]*m[15] + m[5]*m[3]*m[14] + m[13]*m[2]*m[7]  - m[13]*m[3]*m[6];
    float i6  = -m[0]*m[6]*m[15]  + m[0]*m[7]*m[14]  + m[4]*m[2]*m[15] - m[4]*m[3]*m[14] - m[12]*m[2]*m[7]  + m[12]*m[3]*m[6];
    float i10 =  m[0]*m[5]*m[15]  - m[0]*m[7]*m[13]  - m[4]*m[1]*m[15] + m[4]*m[3]*m[13] + m[12]*m[1]*m[7]  - m[12]*m[3]*m[5];

    float det = m[0]*i0 + m[1]*i4 + m[2]*i8 + m[3]*i12;
    float id = 1.0f / det;
    rinv[v*9+0] = i0*id;  rinv[v*9+1] = i1*id;  rinv[v*9+2] = i2*id;
    rinv[v*9+3] = i4*id;  rinv[v*9+4] = i5*id;  rinv[v*9+5] = i6*id;
    rinv[v*9+6] = i8*id;  rinv[v*9+7] = i9*id;  rinv[v*9+8] = i10*id;

    float kx = keyp[v*3], ky = keyp[v*3+1], kz = keyp[v*3+2];
    kp4[v] = make_float4(kx, ky, kz, kx*kx + ky*ky + kz*kz);
}

// ---------------- weight convert: fp32 W[k][n] -> bf16 Wt[n][k] (padded) ----------------
__global__ __launch_bounds__(256) void wconv_kernel(
    const float* __restrict__ W1, const float* __restrict__ W2,
    const float* __restrict__ W3, unsigned short* __restrict__ wt1,
    unsigned short* __restrict__ wt2, unsigned short* __restrict__ wt3)
{
    int idx = blockIdx.x * 256 + threadIdx.x;
    const int N1 = 256 * D_INP;          // 180224
    const int N2 = 256 * 256;            // 65536
    if (idx < N1) {
        int n = idx / D_INP, k = idx - n * D_INP;
        float v = (k < D_IN) ? W1[k * 256 + n] : 0.0f;
        wt1[n * D_INP + k] = f2bf(v);
    } else if (idx < N1 + N2) {
        int t = idx - N1;
        int n = t >> 8, k = t & 255;
        wt2[n * 256 + k] = f2bf(W2[k * 256 + n]);
    } else if (idx < N1 + 2 * N2) {
        int t = idx - N1 - N2;
        int n = t >> 8, k = t & 255;
        wt3[n * 256 + k] = f2bf(W3[k * 256 + n]);
    }
}

// ---------------- KNN: fp32 scan + fp64 refine of near-ties ----------------
// fp64 values computed identically to the always-fp64 version (which passed),
// so cross-chunk reduction and the final argmin decision are unchanged.
__global__ __launch_bounds__(256) void knn_part_kernel(
    const float* __restrict__ pts, const float4* __restrict__ kp4,
    double* __restrict__ pd, int* __restrict__ pi)
{
    int n = blockIdx.x * 256 + threadIdx.x;
    int c = blockIdx.y;
    int v0 = c * CHUNK;
    int v1 = min(V_N, v0 + CHUNK);

    float px = pts[n*6+0], py = pts[n*6+1], pz = pts[n*6+2];
    float pp = px*px + py*py + pz*pz;

    // phase 1: fp32 min, 4 independent chains (kp4[i] is wave-uniform -> s_load)
    float b0 = 1e30f, b1 = 1e30f, b2 = 1e30f, b3 = 1e30f;
    int i = v0;
    for (; i + 4 <= v1; i += 4) {
        float4 k0 = kp4[i], k1 = kp4[i+1], k2 = kp4[i+2], k3 = kp4[i+3];
        float d0 = (pp + k0.w) - 2.0f*(px*k0.x + py*k0.y + pz*k0.z);
        float d1 = (pp + k1.w) - 2.0f*(px*k1.x + py*k1.y + pz*k1.z);
        float d2 = (pp + k2.w) - 2.0f*(px*k2.x + py*k2.y + pz*k2.z);
        float d3 = (pp + k3.w) - 2.0f*(px*k3.x + py*k3.y + pz*k3.z);
        b0 = fminf(b0, d0); b1 = fminf(b1, d1);
        b2 = fminf(b2, d2); b3 = fminf(b3, d3);
    }
    for (; i < v1; ++i) {
        float4 k0 = kp4[i];
        float d0 = (pp + k0.w) - 2.0f*(px*k0.x + py*k0.y + pz*k0.z);
        b0 = fminf(b0, d0);
    }
    float thresh = fminf(fminf(b0, b1), fminf(b2, b3)) + 1e-3f;

    // phase 2: exact fp64 on candidates within margin (rare branch)
    double pxd = (double)px, pyd = (double)py, pzd = (double)pz;
    double ppd = pxd*pxd + pyd*pyd + pzd*pzd;
    double best = 1e300; int bi = 0x7fffffff;
    for (i = v0; i < v1; ++i) {
        float4 k0 = kp4[i];
        float d32 = (pp + k0.w) - 2.0f*(px*k0.x + py*k0.y + pz*k0.z);
        if (d32 <= thresh) {
            double kx = (double)k0.x, ky = (double)k0.y, kz = (double)k0.z;
            double d = ppd - 2.0*(pxd*kx + pyd*ky + pzd*kz) + (kx*kx + ky*ky + kz*kz);
            if (d < best) { best = d; bi = i; }   // i increasing -> first-min tiebreak
        }
    }
    pd[(size_t)n*NCHUNK + c] = best;
    pi[(size_t)n*NCHUNK + c] = bi;
}

__global__ __launch_bounds__(256) void knn_reduce_kernel(
    const double* __restrict__ pd, const int* __restrict__ pi, int* __restrict__ knn)
{
    int n = blockIdx.x * 256 + threadIdx.x;
    double best = 1e300; int bi = 0x7fffffff;
#pragma unroll
    for (int c = 0; c < NCHUNK; ++c) {
        double d = pd[(size_t)n*NCHUNK + c];
        int    i = pi[(size_t)n*NCHUNK + c];
        if (d < best || (d == best && i < bi)) { best = d; bi = i; }
    }
    knn[n] = bi;
}

// ---------------- features: X row (bf16, 704 padded) + direction posenc tail ----------------
__global__ __launch_bounds__(256) void feat_kernel(
    const float* __restrict__ pts, const float* __restrict__ keyp,
    const int* __restrict__ neigh, const float* __restrict__ restp,
    const float* __restrict__ latent, const float* __restrict__ rinv,
    const int* __restrict__ knn, unsigned short* __restrict__ X,
    float* __restrict__ out)
{
    int w = threadIdx.x >> 6;       // wave in block
    int lane = threadIdx.x & 63;
    int n = blockIdx.x * 4 + w;     // point id

    __shared__ float s_vf[4][28];
    __shared__ int   s_vi[4][8];
    __shared__ float s_dir[4][4];

    int k = knn[n];
    float px = pts[n*6+0], py = pts[n*6+1], pz = pts[n*6+2];

    if (lane < 7) {
        int v = neigh[k*7 + lane];
        s_vi[w][lane] = v;
        float dx = px - keyp[v*3+0];
        float dy = py - keyp[v*3+1];
        float dz = pz - keyp[v*3+2];
        s_vf[w][21 + lane] = sqrtf(dx*dx + dy*dy + dz*dz);
    }
    if (lane == 7) {
        float dx = px - keyp[k*3+0];
        float dy = py - keyp[k*3+1];
        float dz = pz - keyp[k*3+2];
        const float* R = &rinv[k*9];
        float d0 = R[0]*dx + R[1]*dy + R[2]*dz;
        float d1 = R[3]*dx + R[4]*dy + R[5]*dz;
        float d2 = R[6]*dx + R[7]*dy + R[8]*dz;
        float nrm = fmaxf(sqrtf(d0*d0 + d1*d1 + d2*d2), 1e-12f);
        s_dir[w][0] = d0/nrm; s_dir[w][1] = d1/nrm; s_dir[w][2] = d2/nrm;
    }
    __syncthreads();
    if (lane < 21) {
        s_vf[w][lane] = restp[s_vi[w][lane/3]*3 + (lane%3)];
    }
    __syncthreads();

    // output tail (fp32): [dir(3), sin f-major (12), cos (12)]
    if (lane < 27) {
        float val;
        if (lane < 3) val = s_dir[w][lane];
        else if (lane < 15) { int t = lane - 3;  val = sinf(s_dir[w][t%3] * (float)(1 << (t/3))); }
        else                { int t = lane - 15; val = cosf(s_dir[w][t%3] * (float)(1 << (t/3))); }
        out[(size_t)n*D_OUT + 256 + lane] = val;
    }

    // X row bf16: [vfeat(28), sin (280), cos (280), lfeat(112), pad(4)=0]
    for (int i = lane; i < D_INP; i += 64) {
        float val;
        if (i < 28) {
            val = s_vf[w][i];
        } else if (i < 308) {
            int t = i - 28;  val = sinf(s_vf[w][t%28] * (float)(1 << (t/28)));
        } else if (i < 588) {
            int t = i - 308; val = cosf(s_vf[w][t%28] * (float)(1 << (t/28)));
        } else if (i < 700) {
            int t = i - 588; val = latent[s_vi[w][t >> 4]*16 + (t & 15)];
        } else {
            val = 0.0f;
        }
        X[(size_t)n*D_INP + i] = f2bf(val);
    }
}

// ---------------- bf16 MFMA GEMM: C = [relu](A @ Wt^T + b) ----------------
// A: N x lda bf16 row-major; Wt: 256 x ldw bf16 (output-col-major rows, k contig)
// block: 512 thr = 8 waves; tile BM=128 x BN=128, BK=32
__global__ __launch_bounds__(512) void mfma_gemm(
    const unsigned short* __restrict__ A, int lda,
    const unsigned short* __restrict__ Wt, int ldw,
    const float* __restrict__ bias,
    void* __restrict__ Cout, int ldc, int K, int relu_bf16out)
{
    __shared__ unsigned short As[128 * 32];   // [m][k], 8KB
    __shared__ unsigned short Bs[128 * 32];   // [n][k], 8KB

    int t = threadIdx.x;
    int bm = blockIdx.x * 128;
    int bn = blockIdx.y * 128;

    int l = t & 63, w = t >> 6;
    int mbase = (w >> 2) * 64;
    int nbase = (w & 3) * 32;
    int lrow = l & 15;
    int lk = (l >> 4) * 8;

    const char* gA0 = (const char*)(A + (size_t)(bm + (t >> 2)) * lda) + (t & 3) * 16;
    const char* gB0 = (const char*)(Wt + (size_t)(bn + (t >> 2)) * ldw) + (t & 3) * 16;
    char* lA = (char*)As + t * 16;
    char* lB = (char*)Bs + t * 16;

    f32x4 acc[4][2];
#pragma unroll
    for (int i = 0; i < 4; ++i)
#pragma unroll
        for (int j = 0; j < 2; ++j) acc[i][j] = {0.f, 0.f, 0.f, 0.f};

    for (int k0 = 0; k0 < K; k0 += 32) {
        glds16(gA0 + (size_t)k0 * 2, lA);
        glds16(gB0 + (size_t)k0 * 2, lB);
        __syncthreads();

        short8 af[4], bf[2];
#pragma unroll
        for (int mi = 0; mi < 4; ++mi)
            af[mi] = *(const short8*)&As[(mbase + mi * 16 + lrow) * 32 + lk];
#pragma unroll
        for (int ni = 0; ni < 2; ++ni)
            bf[ni] = *(const short8*)&Bs[(nbase + ni * 16 + lrow) * 32 + lk];

#pragma unroll
        for (int mi = 0; mi < 4; ++mi)
#pragma unroll
            for (int ni = 0; ni < 2; ++ni)
                acc[mi][ni] = __builtin_amdgcn_mfma_f32_16x16x32_bf16(
                    af[mi], bf[ni], acc[mi][ni], 0, 0, 0);
        __syncthreads();
    }

    // epilogue: C/D layout col=lane&15, row=(lane>>4)*4+reg
#pragma unroll
    for (int mi = 0; mi < 4; ++mi) {
#pragma unroll
        for (int ni = 0; ni < 2; ++ni) {
            int col = bn + nbase + ni * 16 + (l & 15);
            float bv = bias[col];
#pragma unroll
            for (int r = 0; r < 4; ++r) {
                int row = bm + mbase + mi * 16 + (l >> 4) * 4 + r;
                float val = acc[mi][ni][r] + bv;
                if (relu_bf16out) {
                    val = fmaxf(val, 0.0f);
                    ((unsigned short*)Cout)[(size_t)row * ldc + col] = f2bf(val);
                } else {
                    ((float*)Cout)[(size_t)row * ldc + col] = val;
                }
            }
        }
    }
}

extern "C" void kernel_launch(void* const* d_in, const int* in_sizes, int n_in,
                              void* d_out, int out_size, void* d_ws, size_t ws_size,
                              hipStream_t stream) {
    const float* pts    = (const float*)d_in[0];
    const float* keyp   = (const float*)d_in[1];
    const float* trans  = (const float*)d_in[2];
    const int*   neigh  = (const int*)d_in[3];
    const float* restp  = (const float*)d_in[4];
    const float* latent = (const float*)d_in[5];
    const float* W1     = (const float*)d_in[6];
    const float* b1     = (const float*)d_in[7];
    const float* W2     = (const float*)d_in[8];
    const float* b2     = (const float*)d_in[9];
    const float* W3     = (const float*)d_in[10];
    const float* b3     = (const float*)d_in[11];
    float* out = (float*)d_out;

    float* wsf = (float*)d_ws;
    float*          rinv = wsf + RINV_OFF;
    float4*         kp4  = (float4*)(wsf + KP4_OFF);
    int*            knn  = (int*)(wsf + KNN_OFF);
    double*         pd   = (double*)(wsf + PD_OFF);
    int*            pi   = (int*)(wsf + PI_OFF);
    unsigned short* wt1  = (unsigned short*)(wsf + WT1_OFF);
    unsigned short* wt2  = (unsigned short*)(wsf + WT2_OFF);
    unsigned short* wt3  = (unsigned short*)(wsf + WT3_OFF);
    unsigned short* X    = (unsigned short*)(wsf + X_OFF);
    unsigned short* H1   = (unsigned short*)(wsf + H1_OFF);
    unsigned short* H2   = (unsigned short*)(wsf + H2_OFF);

    prep_kernel<<<(V_N + 255)/256, 256, 0, stream>>>(trans, keyp, rinv, kp4);
    wconv_kernel<<<(256*D_INP + 2*256*256 + 255)/256, 256, 0, stream>>>(
        W1, W2, W3, wt1, wt2, wt3);
    knn_part_kernel<<<dim3(N_PTS/256, NCHUNK), 256, 0, stream>>>(pts, kp4, pd, pi);
    knn_reduce_kernel<<<N_PTS/256, 256, 0, stream>>>(pd, pi, knn);
    feat_kernel<<<N_PTS/4, 256, 0, stream>>>(pts, keyp, neigh, restp, latent, rinv, knn, X, out);

    mfma_gemm<<<dim3(N_PTS/128, 2), 512, 0, stream>>>(X,  D_INP, wt1, D_INP, b1, H1,  256, D_INP, 1);
    mfma_gemm<<<dim3(N_PTS/128, 2), 512, 0, stream>>>(H1, D_HID, wt2, D_HID, b2, H2,  256, D_HID, 1);
    mfma_gemm<<<dim3(N_PTS/128, 2), 512, 0, stream>>>(H2, D_HID, wt3, D_HID, b3, out, D_OUT, D_HID, 0);
}